// Round 9
// baseline (86.229 us; speedup 1.0000x reference)
//
#include <hip/hip_runtime.h>
#include <hip/hip_bf16.h>

#define T_LEN   200
#define NTILES  13     // ceil(200/16)

typedef __bf16 bf16x8 __attribute__((ext_vector_type(8)));
typedef __bf16 bf16x4 __attribute__((ext_vector_type(4)));
typedef float  f32x4  __attribute__((ext_vector_type(4)));

#if __has_builtin(__builtin_amdgcn_mfma_f32_16x16x16_bf16)
#define MFMA16(a, b, c) __builtin_amdgcn_mfma_f32_16x16x16_bf16((a), (b), (c), 0, 0, 0)
#elif __has_builtin(__builtin_amdgcn_mfma_f32_16x16x16bf16_1k)
#define MFMA16(a, b, c) __builtin_amdgcn_mfma_f32_16x16x16bf16_1k((a), (b), (c), 0, 0, 0)
#else
static __device__ __forceinline__ f32x4 mfma16_asm(bf16x4 a, bf16x4 b, f32x4 c) {
  asm("v_mfma_f32_16x16x16_bf16 %0, %1, %2, %0" : "+v"(c) : "v"(a), "v"(b));
  return c;
}
#define MFMA16(a, b, c) mfma16_asm((a), (b), (c))
#endif

#define MFMA32(a, b, c) __builtin_amdgcn_mfma_f32_16x16x32_bf16((a), (b), (c), 0, 0, 0)

// d_ws layout (bytes):
//   [0,      8192)  w1acP : bf16 per-lane A-frag order [lane][frag(8)][e(8)]  (W1a+W1c)
//   [8192,  16384)  w1dP  : bf16 same order                                   (W1d)
//   [16384, 20480)  w2P   : bf16 per-lane frag order [lane][frag(8)][i(4)]    (layer-2 A-op)
//   [20480, 36864)  wdiffT: f32 [j(64)][d(64)]                                (W1b-W1c)

__global__ __launch_bounds__(256) void prep_kernel(
    const float* __restrict__ W1g, const float* __restrict__ W2g,
    unsigned char* __restrict__ ws)
{
  const int idx = blockIdx.x * 256 + threadIdx.x;   // 0..4095
  unsigned short* w1acP = (unsigned short*)(ws);
  unsigned short* w1dP  = (unsigned short*)(ws + 8192);
  unsigned short* w2P   = (unsigned short*)(ws + 16384);
  float*          wdifT = (float*)(ws + 20480);
  {
    // A-fragment pack: lane l=(g,r), frag f=(jt,kc), elem e
    int l = idx >> 6, q = idx & 63;
    int f = q >> 3, e = q & 7;
    int jt = f >> 1, kc = f & 1;
    int g = l >> 4, r = l & 15;
    int j = jt * 16 + r;
    int d = kc * 32 + g * 8 + e;
    float ac = W1g[d * 64 + j] + W1g[(128 + d) * 64 + j];
    float dd = W1g[(192 + d) * 64 + j];
    __bf16 acb = (__bf16)ac, ddb = (__bf16)dd;
    w1acP[l * 64 + f * 8 + e] = *(unsigned short*)&acb;
    w1dP [l * 64 + f * 8 + e] = *(unsigned short*)&ddb;
  }
  if (idx < 2048) {
    // layer-2 weight pack (used as MFMA A-operand): frag f = nt*4+c, elem i
    int l = idx >> 5, q = idx & 31;
    int f = q >> 2, i = q & 3;
    int nt = f >> 2, c = f & 3;
    int g = l >> 4, r = l & 15;
    __bf16 v = (__bf16)W2g[(c * 16 + g * 4 + i) * 32 + nt * 16 + r];
    w2P[l * 32 + f * 4 + i] = *(unsigned short*)&v;
  }
  {
    int j = idx & 63, d = idx >> 6;
    wdifT[j * 64 + d] = W1g[(64 + d) * 64 + j] - W1g[(128 + d) * 64 + j];
  }
}

__device__ __forceinline__ void loadA(const float* __restrict__ behB, int t, int kb,
                                      f32x4 (&x)[4]) {
  if (t < T_LEN) {
    const float* p = behB + (size_t)t * 64 + kb;
    x[0] = *(const f32x4*)p;
    x[1] = *(const f32x4*)(p + 4);
    x[2] = *(const f32x4*)(p + 32);
    x[3] = *(const f32x4*)(p + 36);
  } else {
    x[0] = f32x4{0.f, 0.f, 0.f, 0.f};
    x[1] = f32x4{0.f, 0.f, 0.f, 0.f};
    x[2] = f32x4{0.f, 0.f, 0.f, 0.f};
    x[3] = f32x4{0.f, 0.f, 0.f, 0.f};
  }
}

__global__ __launch_bounds__(64, 4) void lau_kernel(
    const float* __restrict__ behG, const float* __restrict__ candG,
    const int*  __restrict__ maskG,
    const float* __restrict__ b1g, const float* __restrict__ a1g,
    const float* __restrict__ b2g, const float* __restrict__ a2g,
    const float* __restrict__ W3g,
    const unsigned char* __restrict__ ws,
    float* __restrict__ outG)
{
  const int lane = threadIdx.x;          // one wave per block
  const int b    = blockIdx.x;           // one batch row per block
  const int r    = lane & 15;
  const int g    = lane >> 4;
  const int kb   = g * 8;

  const unsigned short* w1acP = (const unsigned short*)(ws);
  const unsigned short* w1dP  = (const unsigned short*)(ws + 8192);
  const unsigned short* w2P   = (const unsigned short*)(ws + 16384);
  const float*          wdifT = (const float*)(ws + 20480);

  // mask dtype detection (wave-uniform)
  const bool boolmask = (__ballot(((const unsigned int*)maskG)[lane] > 1u) != 0ull);

  // fold this lane's 13 mask values into a bitmask (no in-loop mask traffic)
  const unsigned char* maskB8 = (const unsigned char*)maskG + (size_t)b * T_LEN;
  const int* maskB32 = maskG + (size_t)b * T_LEN;
  unsigned mbits = 0;
#pragma unroll
  for (int mt = 0; mt < NTILES; ++mt) {
    int t = mt * 16 + r;
    int mv = 0;
    if (t < T_LEN) mv = boolmask ? (int)maskB8[t] : maskB32[t];
    mbits |= (mv != 0 ? 1u : 0u) << mt;
  }

  // candidate chunks for this lane's d-columns
  const float* candB = candG + (size_t)b * 64;
  const f32x4 c0a = *(const f32x4*)(candB + kb);
  const f32x4 c0b = *(const f32x4*)(candB + kb + 4);
  const f32x4 c1a = *(const f32x4*)(candB + kb + 32);
  const f32x4 c1b = *(const f32x4*)(candB + kb + 36);

  // loop-invariant layer-1 A-fragments: W1eff^T = (W1a+W1c) + cand_d * W1d
  bf16x8 A1[4][2];
#pragma unroll
  for (int f = 0; f < 8; ++f) {
    const int jt = f >> 1, kc = f & 1;
    bf16x8 ac = *(const bf16x8*)(w1acP + lane * 64 + f * 8);
    bf16x8 dd = *(const bf16x8*)(w1dP  + lane * 64 + f * 8);
    f32x4 cA = kc ? c1a : c0a;
    f32x4 cB = kc ? c1b : c0b;
    bf16x8 o;
#pragma unroll
    for (int e = 0; e < 4; ++e) {
      o[e]     = (__bf16)((float)ac[e]     + cA[e] * (float)dd[e]);
      o[4 + e] = (__bf16)((float)ac[4 + e] + cB[e] * (float)dd[4 + e]);
    }
    A1[jt][kc] = o;
  }

  // layer-2 weight fragments (MFMA A-operand), pre-packed
  bf16x4 W2f[8];
#pragma unroll
  for (int f = 0; f < 8; ++f)
    W2f[f] = *(const bf16x4*)(w2P + lane * 32 + f * 4);

  // exact f32 bias: b1 + cand @ (W1b - W1c)
  float biasv = b1g[lane];
  {
    const float* wdrow = wdifT + lane * 64;
#pragma unroll
    for (int d4 = 0; d4 < 16; ++d4) {
      f32x4 wd = *(const f32x4*)(wdrow + d4 * 4);
      f32x4 cd = *(const f32x4*)(candB + d4 * 4);
      biasv += wd[0] * cd[0] + wd[1] * cd[1] + wd[2] * cd[2] + wd[3] * cd[3];
    }
  }
  // per-lane bias rows for layer-1 C-init: bias[j = jt*16 + g*4 + i]
  f32x4 bj4[4];
#pragma unroll
  for (int jt = 0; jt < 4; ++jt)
#pragma unroll
    for (int i = 0; i < 4; ++i)
      bj4[jt][i] = __shfl(biasv, jt * 16 + g * 4 + i);

  const float al1 = a1g[0];
  const float al2 = a2g[0];
  const f32x4 cinit0 = *(const f32x4*)(b2g + g * 4);
  const f32x4 cinit1 = *(const f32x4*)(b2g + 16 + g * 4);
  const f32x4 w3f0   = *(const f32x4*)(W3g + g * 4);
  const f32x4 w3f1   = *(const f32x4*)(W3g + 16 + g * 4);

  const float* behB = behG + (size_t)b * T_LEN * 64;

  // per-lane online-softmax state (lane owns t = mt*16 + r)
  float mrun = -__builtin_inff();
  float srun = 0.f;
  f32x4 o0 = {0,0,0,0}, o1 = {0,0,0,0}, o2 = {0,0,0,0}, o3 = {0,0,0,0};

  f32x4 xc[4];
  loadA(behB, r, kb, xc);

#pragma unroll 1
  for (int mt = 0; mt < NTILES; ++mt) {
    // convert current tile to bf16 fragments, then reuse xc for prefetch
    bf16x8 ab0, ab1;
#pragma unroll
    for (int i = 0; i < 4; ++i) {
      ab0[i]     = (__bf16)xc[0][i];
      ab0[4 + i] = (__bf16)xc[1][i];
      ab1[i]     = (__bf16)xc[2][i];
      ab1[4 + i] = (__bf16)xc[3][i];
    }
    if (mt + 1 < NTILES) {
      int tn = (mt + 1) * 16 + r;
      loadA(behB, tn, kb, xc);
    }

    // ---- layer 1 (swapped: D1[j][t]), bias via MFMA C-in ----
    bf16x4 a2f[4];
#pragma unroll
    for (int jt = 0; jt < 4; ++jt) {
      f32x4 acc = MFMA32(A1[jt][0], ab0, bj4[jt]);
      acc = MFMA32(A1[jt][1], ab1, acc);
#pragma unroll
      for (int i = 0; i < 4; ++i) {
        float h = acc[i];
        h = (h >= 0.f) ? h : al1 * h;
        a2f[jt][i] = (__bf16)h;
      }
    }

    // ---- layer 2 SWAPPED: D2[j2][t] = W2^T · h1^T  (W2f as A, a2f as B) ----
    f32x4 acc20 = cinit0, acc21 = cinit1;
#pragma unroll
    for (int c = 0; c < 4; ++c) acc20 = MFMA16(W2f[c],     a2f[c], acc20);
#pragma unroll
    for (int c = 0; c < 4; ++c) acc21 = MFMA16(W2f[4 + c], a2f[c], acc21);

    // ---- layer 3: in-lane dot over this lane's 8 j2's, then 2-step g-reduce ----
    float partial = 0.f;
#pragma unroll
    for (int i = 0; i < 4; ++i) {
      float h0 = acc20[i]; h0 = (h0 >= 0.f) ? h0 : al2 * h0;
      float h1 = acc21[i]; h1 = (h1 >= 0.f) ? h1 : al2 * h1;
      partial += h0 * w3f0[i] + h1 * w3f1[i];
    }
    partial += __shfl_xor(partial, 16);
    partial += __shfl_xor(partial, 32);
    // partial = logit[t = mt*16 + r], replicated across g

    // ---- per-lane online softmax (defer-max, threshold 8) ----
    const bool valid = ((mbits >> mt) & 1u) != 0u;
    float lvt = valid ? partial : -__builtin_inff();
    if (lvt > mrun + 8.f) {          // rare after first tile
      float fs = __expf(mrun - lvt); // mrun=-inf -> 0 (zeroes empty state)
      srun *= fs;
#pragma unroll
      for (int i = 0; i < 4; ++i) { o0[i] *= fs; o1[i] *= fs; o2[i] *= fs; o3[i] *= fs; }
      mrun = lvt;
    }
    float et = valid ? __expf(lvt - mrun) : 0.f;
    srun += et;
#pragma unroll
    for (int i = 0; i < 4; ++i) {
      o0[i] += et * (float)ab0[i];
      o1[i] += et * (float)ab0[4 + i];
      o2[i] += et * (float)ab1[i];
      o3[i] += et * (float)ab1[4 + i];
    }
  }

  // ---- epilogue: merge the 16 per-lane states across r ----
  float M = mrun;
#pragma unroll
  for (int off = 1; off < 16; off <<= 1) M = fmaxf(M, __shfl_xor(M, off));
  {
    float fac = __expf(mrun - M);   // never-valid lane: exp(-inf)=0
    srun *= fac;
#pragma unroll
    for (int i = 0; i < 4; ++i) { o0[i] *= fac; o1[i] *= fac; o2[i] *= fac; o3[i] *= fac; }
  }
#pragma unroll
  for (int off = 1; off < 16; off <<= 1) {
#pragma unroll
    for (int i = 0; i < 4; ++i) {
      o0[i] += __shfl_xor(o0[i], off);
      o1[i] += __shfl_xor(o1[i], off);
      o2[i] += __shfl_xor(o2[i], off);
      o3[i] += __shfl_xor(o3[i], off);
    }
    srun += __shfl_xor(srun, off);
  }
  if (r == 0) {
    float inv = 1.f / srun;
    float* po = outG + (size_t)b * 64 + kb;
#pragma unroll
    for (int i = 0; i < 4; ++i) {
      o0[i] *= inv; o1[i] *= inv; o2[i] *= inv; o3[i] *= inv;
    }
    *(f32x4*)(po)      = o0;
    *(f32x4*)(po + 4)  = o1;
    *(f32x4*)(po + 32) = o2;
    *(f32x4*)(po + 36) = o3;
  }
}

extern "C" void kernel_launch(void* const* d_in, const int* in_sizes, int n_in,
                              void* d_out, int out_size, void* d_ws, size_t ws_size,
                              hipStream_t stream) {
  (void)n_in; (void)ws_size; (void)out_size;
  const float* beh  = (const float*)d_in[0];
  const float* cand = (const float*)d_in[1];
  const int*   mask = (const int*)d_in[2];
  const float* W1   = (const float*)d_in[3];
  const float* b1   = (const float*)d_in[4];
  const float* a1   = (const float*)d_in[5];
  const float* W2   = (const float*)d_in[6];
  const float* b2   = (const float*)d_in[7];
  const float* a2   = (const float*)d_in[8];
  const float* W3   = (const float*)d_in[9];
  // d_in[10] (b3): uniform additive bias cancels in softmax

  unsigned char* ws = (unsigned char*)d_ws;
  prep_kernel<<<16, 256, 0, stream>>>(W1, W2, ws);

  int B = in_sizes[1] / 64;   // 4096
  lau_kernel<<<B, 64, 0, stream>>>(beh, cand, mask, b1, a1, b2, a2, W3,
                                   ws, (float*)d_out);
}

// Round 10
// 66.507 us; speedup vs baseline: 1.2965x; 1.2965x over previous
//
#include <hip/hip_runtime.h>
#include <hip/hip_bf16.h>

#define T_LEN   200
#define NTILES  13     // ceil(200/16)

typedef __bf16 bf16x8 __attribute__((ext_vector_type(8)));
typedef __bf16 bf16x4 __attribute__((ext_vector_type(4)));
typedef float  f32x4  __attribute__((ext_vector_type(4)));

#if __has_builtin(__builtin_amdgcn_mfma_f32_16x16x16_bf16)
#define MFMA16(a, b, c) __builtin_amdgcn_mfma_f32_16x16x16_bf16((a), (b), (c), 0, 0, 0)
#elif __has_builtin(__builtin_amdgcn_mfma_f32_16x16x16bf16_1k)
#define MFMA16(a, b, c) __builtin_amdgcn_mfma_f32_16x16x16bf16_1k((a), (b), (c), 0, 0, 0)
#else
static __device__ __forceinline__ f32x4 mfma16_asm(bf16x4 a, bf16x4 b, f32x4 c) {
  asm("v_mfma_f32_16x16x16_bf16 %0, %1, %2, %0" : "+v"(c) : "v"(a), "v"(b));
  return c;
}
#define MFMA16(a, b, c) mfma16_asm((a), (b), (c))
#endif

#define MFMA32(a, b, c) __builtin_amdgcn_mfma_f32_16x16x32_bf16((a), (b), (c), 0, 0, 0)

// d_ws layout (bytes):
//   [0,      8192)  w1acP : bf16 per-lane A-frag order [lane][frag(8)][e(8)]  (W1a+W1c)
//   [8192,  16384)  w1dP  : bf16 same order                                   (W1d)
//   [16384, 20480)  w2P   : bf16 per-lane frag order [lane][frag(8)][i(4)]    (layer-2 A-op)
//   [20480, 36864)  wdiffT: f32 [j(64)][d(64)]                                (W1b-W1c)

__global__ __launch_bounds__(256) void prep_kernel(
    const float* __restrict__ W1g, const float* __restrict__ W2g,
    unsigned char* __restrict__ ws)
{
  const int idx = blockIdx.x * 256 + threadIdx.x;   // 0..4095
  unsigned short* w1acP = (unsigned short*)(ws);
  unsigned short* w1dP  = (unsigned short*)(ws + 8192);
  unsigned short* w2P   = (unsigned short*)(ws + 16384);
  float*          wdifT = (float*)(ws + 20480);
  {
    // A-fragment pack: lane l=(g,r), frag f=(jt,kc), elem e
    int l = idx >> 6, q = idx & 63;
    int f = q >> 3, e = q & 7;
    int jt = f >> 1, kc = f & 1;
    int g = l >> 4, r = l & 15;
    int j = jt * 16 + r;
    int d = kc * 32 + g * 8 + e;
    float ac = W1g[d * 64 + j] + W1g[(128 + d) * 64 + j];
    float dd = W1g[(192 + d) * 64 + j];
    __bf16 acb = (__bf16)ac, ddb = (__bf16)dd;
    w1acP[l * 64 + f * 8 + e] = *(unsigned short*)&acb;
    w1dP [l * 64 + f * 8 + e] = *(unsigned short*)&ddb;
  }
  if (idx < 2048) {
    // layer-2 weight pack (used as MFMA A-operand): frag f = nt*4+c, elem i
    int l = idx >> 5, q = idx & 31;
    int f = q >> 2, i = q & 3;
    int nt = f >> 2, c = f & 3;
    int g = l >> 4, r = l & 15;
    __bf16 v = (__bf16)W2g[(c * 16 + g * 4 + i) * 32 + nt * 16 + r];
    w2P[l * 32 + f * 4 + i] = *(unsigned short*)&v;
  }
  {
    int j = idx & 63, d = idx >> 6;
    wdifT[j * 64 + d] = W1g[(64 + d) * 64 + j] - W1g[(128 + d) * 64 + j];
  }
}

__device__ __forceinline__ void loadA(const float* __restrict__ behB, int t, int kb,
                                      f32x4 (&x)[4]) {
  if (t < T_LEN) {
    const float* p = behB + (size_t)t * 64 + kb;
    x[0] = *(const f32x4*)p;
    x[1] = *(const f32x4*)(p + 4);
    x[2] = *(const f32x4*)(p + 32);
    x[3] = *(const f32x4*)(p + 36);
  } else {
    x[0] = f32x4{0.f, 0.f, 0.f, 0.f};
    x[1] = f32x4{0.f, 0.f, 0.f, 0.f};
    x[2] = f32x4{0.f, 0.f, 0.f, 0.f};
    x[3] = f32x4{0.f, 0.f, 0.f, 0.f};
  }
}

__global__ __launch_bounds__(64) void lau_kernel(
    const float* __restrict__ behG, const float* __restrict__ candG,
    const int*  __restrict__ maskG,
    const float* __restrict__ b1g, const float* __restrict__ a1g,
    const float* __restrict__ b2g, const float* __restrict__ a2g,
    const float* __restrict__ W3g,
    const unsigned char* __restrict__ ws,
    float* __restrict__ outG)
{
  const int lane = threadIdx.x;          // one wave per block
  const int b    = blockIdx.x;           // one batch row per block
  const int r    = lane & 15;
  const int g    = lane >> 4;
  const int kb   = g * 8;

  const unsigned short* w1acP = (const unsigned short*)(ws);
  const unsigned short* w1dP  = (const unsigned short*)(ws + 8192);
  const unsigned short* w2P   = (const unsigned short*)(ws + 16384);
  const float*          wdifT = (const float*)(ws + 20480);

  // mask dtype detection (wave-uniform)
  const bool boolmask = (__ballot(((const unsigned int*)maskG)[lane] > 1u) != 0ull);

  // fold this lane's 13 mask values into a bitmask (no in-loop mask traffic)
  const unsigned char* maskB8 = (const unsigned char*)maskG + (size_t)b * T_LEN;
  const int* maskB32 = maskG + (size_t)b * T_LEN;
  unsigned mbits = 0;
#pragma unroll
  for (int mt = 0; mt < NTILES; ++mt) {
    int t = mt * 16 + r;
    int mv = 0;
    if (t < T_LEN) mv = boolmask ? (int)maskB8[t] : maskB32[t];
    mbits |= (mv != 0 ? 1u : 0u) << mt;
  }

  // candidate chunks for this lane's d-columns
  const float* candB = candG + (size_t)b * 64;
  const f32x4 c0a = *(const f32x4*)(candB + kb);
  const f32x4 c0b = *(const f32x4*)(candB + kb + 4);
  const f32x4 c1a = *(const f32x4*)(candB + kb + 32);
  const f32x4 c1b = *(const f32x4*)(candB + kb + 36);

  // loop-invariant layer-1 A-fragments: W1eff^T = (W1a+W1c) + cand_d * W1d
  bf16x8 A1[4][2];
#pragma unroll
  for (int f = 0; f < 8; ++f) {
    const int jt = f >> 1, kc = f & 1;
    bf16x8 ac = *(const bf16x8*)(w1acP + lane * 64 + f * 8);
    bf16x8 dd = *(const bf16x8*)(w1dP  + lane * 64 + f * 8);
    f32x4 cA = kc ? c1a : c0a;
    f32x4 cB = kc ? c1b : c0b;
    bf16x8 o;
#pragma unroll
    for (int e = 0; e < 4; ++e) {
      o[e]     = (__bf16)((float)ac[e]     + cA[e] * (float)dd[e]);
      o[4 + e] = (__bf16)((float)ac[4 + e] + cB[e] * (float)dd[4 + e]);
    }
    A1[jt][kc] = o;
  }

  // layer-2 weight fragments (MFMA A-operand), pre-packed
  bf16x4 W2f[8];
#pragma unroll
  for (int f = 0; f < 8; ++f)
    W2f[f] = *(const bf16x4*)(w2P + lane * 32 + f * 4);

  // exact f32 bias: b1 + cand @ (W1b - W1c)
  float biasv = b1g[lane];
  {
    const float* wdrow = wdifT + lane * 64;
#pragma unroll
    for (int d4 = 0; d4 < 16; ++d4) {
      f32x4 wd = *(const f32x4*)(wdrow + d4 * 4);
      f32x4 cd = *(const f32x4*)(candB + d4 * 4);
      biasv += wd[0] * cd[0] + wd[1] * cd[1] + wd[2] * cd[2] + wd[3] * cd[3];
    }
  }
  // per-lane bias rows for layer-1 C-init: bias[j = jt*16 + g*4 + i]
  f32x4 bj4[4];
#pragma unroll
  for (int jt = 0; jt < 4; ++jt)
#pragma unroll
    for (int i = 0; i < 4; ++i)
      bj4[jt][i] = __shfl(biasv, jt * 16 + g * 4 + i);

  const float al1 = a1g[0];
  const float al2 = a2g[0];
  const f32x4 cinit0 = *(const f32x4*)(b2g + g * 4);
  const f32x4 cinit1 = *(const f32x4*)(b2g + 16 + g * 4);
  const f32x4 w3f0   = *(const f32x4*)(W3g + g * 4);
  const f32x4 w3f1   = *(const f32x4*)(W3g + 16 + g * 4);

  const float* behB = behG + (size_t)b * T_LEN * 64;

  // per-lane online-softmax state (lane owns t = mt*16 + r)
  float mrun = -__builtin_inff();
  float srun = 0.f;
  f32x4 o0 = {0,0,0,0}, o1 = {0,0,0,0}, o2 = {0,0,0,0}, o3 = {0,0,0,0};

  f32x4 xc[4];
  loadA(behB, r, kb, xc);

#pragma unroll 1
  for (int mt = 0; mt < NTILES; ++mt) {
    // convert current tile to bf16 fragments, then reuse xc for prefetch
    bf16x8 ab0, ab1;
#pragma unroll
    for (int i = 0; i < 4; ++i) {
      ab0[i]     = (__bf16)xc[0][i];
      ab0[4 + i] = (__bf16)xc[1][i];
      ab1[i]     = (__bf16)xc[2][i];
      ab1[4 + i] = (__bf16)xc[3][i];
    }
    if (mt + 1 < NTILES) {
      int tn = (mt + 1) * 16 + r;
      loadA(behB, tn, kb, xc);
    }

    // ---- layer 1 (swapped: D1[j][t]), bias via MFMA C-in ----
    bf16x4 a2f[4];
#pragma unroll
    for (int jt = 0; jt < 4; ++jt) {
      f32x4 acc = MFMA32(A1[jt][0], ab0, bj4[jt]);
      acc = MFMA32(A1[jt][1], ab1, acc);
#pragma unroll
      for (int i = 0; i < 4; ++i) {
        float h = acc[i];
        h = (h >= 0.f) ? h : al1 * h;
        a2f[jt][i] = (__bf16)h;
      }
    }

    // ---- layer 2 SWAPPED: D2[j2][t] = W2^T · h1^T  (W2f as A, a2f as B) ----
    f32x4 acc20 = cinit0, acc21 = cinit1;
#pragma unroll
    for (int c = 0; c < 4; ++c) acc20 = MFMA16(W2f[c],     a2f[c], acc20);
#pragma unroll
    for (int c = 0; c < 4; ++c) acc21 = MFMA16(W2f[4 + c], a2f[c], acc21);

    // ---- layer 3: in-lane dot over this lane's 8 j2's, then 2-step g-reduce ----
    float partial = 0.f;
#pragma unroll
    for (int i = 0; i < 4; ++i) {
      float h0 = acc20[i]; h0 = (h0 >= 0.f) ? h0 : al2 * h0;
      float h1 = acc21[i]; h1 = (h1 >= 0.f) ? h1 : al2 * h1;
      partial += h0 * w3f0[i] + h1 * w3f1[i];
    }
    partial += __shfl_xor(partial, 16);
    partial += __shfl_xor(partial, 32);
    // partial = logit[t = mt*16 + r], replicated across g

    // ---- per-lane online softmax (defer-max, threshold 8) ----
    const bool valid = ((mbits >> mt) & 1u) != 0u;
    float lvt = valid ? partial : -__builtin_inff();
    if (lvt > mrun + 8.f) {          // rare after first tile
      float fs = __expf(mrun - lvt); // mrun=-inf -> 0 (zeroes empty state)
      srun *= fs;
#pragma unroll
      for (int i = 0; i < 4; ++i) { o0[i] *= fs; o1[i] *= fs; o2[i] *= fs; o3[i] *= fs; }
      mrun = lvt;
    }
    float et = valid ? __expf(lvt - mrun) : 0.f;
    srun += et;
#pragma unroll
    for (int i = 0; i < 4; ++i) {
      o0[i] += et * (float)ab0[i];
      o1[i] += et * (float)ab0[4 + i];
      o2[i] += et * (float)ab1[i];
      o3[i] += et * (float)ab1[4 + i];
    }
  }

  // ---- epilogue: merge the 16 per-lane states across r ----
  float M = mrun;
#pragma unroll
  for (int off = 1; off < 16; off <<= 1) M = fmaxf(M, __shfl_xor(M, off));
  {
    float fac = __expf(mrun - M);   // never-valid lane: exp(-inf)=0
    srun *= fac;
#pragma unroll
    for (int i = 0; i < 4; ++i) { o0[i] *= fac; o1[i] *= fac; o2[i] *= fac; o3[i] *= fac; }
  }
#pragma unroll
  for (int off = 1; off < 16; off <<= 1) {
#pragma unroll
    for (int i = 0; i < 4; ++i) {
      o0[i] += __shfl_xor(o0[i], off);
      o1[i] += __shfl_xor(o1[i], off);
      o2[i] += __shfl_xor(o2[i], off);
      o3[i] += __shfl_xor(o3[i], off);
    }
    srun += __shfl_xor(srun, off);
  }
  if (r == 0) {
    float inv = 1.f / srun;
    float* po = outG + (size_t)b * 64 + kb;
#pragma unroll
    for (int i = 0; i < 4; ++i) {
      o0[i] *= inv; o1[i] *= inv; o2[i] *= inv; o3[i] *= inv;
    }
    *(f32x4*)(po)      = o0;
    *(f32x4*)(po + 4)  = o1;
    *(f32x4*)(po + 32) = o2;
    *(f32x4*)(po + 36) = o3;
  }
}

extern "C" void kernel_launch(void* const* d_in, const int* in_sizes, int n_in,
                              void* d_out, int out_size, void* d_ws, size_t ws_size,
                              hipStream_t stream) {
  (void)n_in; (void)ws_size; (void)out_size;
  const float* beh  = (const float*)d_in[0];
  const float* cand = (const float*)d_in[1];
  const int*   mask = (const int*)d_in[2];
  const float* W1   = (const float*)d_in[3];
  const float* b1   = (const float*)d_in[4];
  const float* a1   = (const float*)d_in[5];
  const float* W2   = (const float*)d_in[6];
  const float* b2   = (const float*)d_in[7];
  const float* a2   = (const float*)d_in[8];
  const float* W3   = (const float*)d_in[9];
  // d_in[10] (b3): uniform additive bias cancels in softmax

  unsigned char* ws = (unsigned char*)d_ws;
  prep_kernel<<<16, 256, 0, stream>>>(W1, W2, ws);

  int B = in_sizes[1] / 64;   // 4096
  lau_kernel<<<B, 64, 0, stream>>>(beh, cand, mask, b1, a1, b2, a2, W3,
                                   ws, (float*)d_out);
}

// Round 11
// 58.010 us; speedup vs baseline: 1.4864x; 1.1465x over previous
//
#include <hip/hip_runtime.h>
#include <hip/hip_bf16.h>

#define T_LEN   200
#define NTILES  13     // ceil(200/16)

typedef __bf16 bf16x8 __attribute__((ext_vector_type(8)));
typedef __bf16 bf16x4 __attribute__((ext_vector_type(4)));
typedef float  f32x4  __attribute__((ext_vector_type(4)));

#if __has_builtin(__builtin_amdgcn_mfma_f32_16x16x16_bf16)
#define MFMA16(a, b, c) __builtin_amdgcn_mfma_f32_16x16x16_bf16((a), (b), (c), 0, 0, 0)
#elif __has_builtin(__builtin_amdgcn_mfma_f32_16x16x16bf16_1k)
#define MFMA16(a, b, c) __builtin_amdgcn_mfma_f32_16x16x16bf16_1k((a), (b), (c), 0, 0, 0)
#else
static __device__ __forceinline__ f32x4 mfma16_asm(bf16x4 a, bf16x4 b, f32x4 c) {
  asm("v_mfma_f32_16x16x16_bf16 %0, %1, %2, %0" : "+v"(c) : "v"(a), "v"(b));
  return c;
}
#define MFMA16(a, b, c) mfma16_asm((a), (b), (c))
#endif

#define MFMA32(a, b, c) __builtin_amdgcn_mfma_f32_16x16x32_bf16((a), (b), (c), 0, 0, 0)

// d_ws layout (bytes):
//   [0,      8192)  w1acP : bf16 per-lane A-frag order [lane][frag(8)][e(8)]  (W1a+W1c)
//   [8192,  16384)  w1dP  : bf16 same order                                   (W1d)
//   [16384, 20480)  w2P   : bf16 per-lane frag order [lane][frag(8)][i(4)]    (layer-2 A-op)
//   [20480, 36864)  wdiffT: f32 [j(64)][d(64)]                                (W1b-W1c)

__global__ __launch_bounds__(256) void prep_kernel(
    const float* __restrict__ W1g, const float* __restrict__ W2g,
    unsigned char* __restrict__ ws)
{
  const int idx = blockIdx.x * 256 + threadIdx.x;   // 0..4095
  unsigned short* w1acP = (unsigned short*)(ws);
  unsigned short* w1dP  = (unsigned short*)(ws + 8192);
  unsigned short* w2P   = (unsigned short*)(ws + 16384);
  float*          wdifT = (float*)(ws + 20480);
  {
    // A-fragment pack: lane l=(g,r), frag f=(jt,kc), elem e
    int l = idx >> 6, q = idx & 63;
    int f = q >> 3, e = q & 7;
    int jt = f >> 1, kc = f & 1;
    int g = l >> 4, r = l & 15;
    int j = jt * 16 + r;
    int d = kc * 32 + g * 8 + e;
    float ac = W1g[d * 64 + j] + W1g[(128 + d) * 64 + j];
    float dd = W1g[(192 + d) * 64 + j];
    __bf16 acb = (__bf16)ac, ddb = (__bf16)dd;
    w1acP[l * 64 + f * 8 + e] = *(unsigned short*)&acb;
    w1dP [l * 64 + f * 8 + e] = *(unsigned short*)&ddb;
  }
  if (idx < 2048) {
    // layer-2 weight pack (used as MFMA A-operand): frag f = nt*4+c, elem i
    int l = idx >> 5, q = idx & 31;
    int f = q >> 2, i = q & 3;
    int nt = f >> 2, c = f & 3;
    int g = l >> 4, r = l & 15;
    __bf16 v = (__bf16)W2g[(c * 16 + g * 4 + i) * 32 + nt * 16 + r];
    w2P[l * 32 + f * 4 + i] = *(unsigned short*)&v;
  }
  {
    int j = idx & 63, d = idx >> 6;
    wdifT[j * 64 + d] = W1g[(64 + d) * 64 + j] - W1g[(128 + d) * 64 + j];
  }
}

__global__ __launch_bounds__(256) void lau_kernel(
    const float* __restrict__ behG, const float* __restrict__ candG,
    const int*  __restrict__ maskG,
    const float* __restrict__ b1g, const float* __restrict__ a1g,
    const float* __restrict__ b2g, const float* __restrict__ a2g,
    const float* __restrict__ W3g,
    const unsigned char* __restrict__ ws,
    float* __restrict__ outG)
{
  // per-wave private double-buffered tile store: 4 waves x 2 bufs x 4 KB = 32 KB
  __shared__ float tb[4][2][1024];

  const int tid  = threadIdx.x;
  const int lane = tid & 63;
  const int wv   = tid >> 6;
  const int b    = blockIdx.x * 4 + wv;   // one wave per batch row
  const int r    = lane & 15;
  const int g    = lane >> 4;
  const int kb   = g * 8;

  const unsigned short* w1acP = (const unsigned short*)(ws);
  const unsigned short* w1dP  = (const unsigned short*)(ws + 8192);
  const unsigned short* w2P   = (const unsigned short*)(ws + 16384);
  const float*          wdifT = (const float*)(ws + 20480);

  // mask dtype detection (wave-uniform)
  const bool boolmask = (__ballot(((const unsigned int*)maskG)[lane] > 1u) != 0ull);

  // fold this lane's 13 mask values into a bitmask (no in-loop mask traffic)
  const unsigned char* maskB8 = (const unsigned char*)maskG + (size_t)b * T_LEN;
  const int* maskB32 = maskG + (size_t)b * T_LEN;
  unsigned mbits = 0;
#pragma unroll
  for (int mt = 0; mt < NTILES; ++mt) {
    int t = mt * 16 + r;
    int mv = 0;
    if (t < T_LEN) mv = boolmask ? (int)maskB8[t] : maskB32[t];
    mbits |= (mv != 0 ? 1u : 0u) << mt;
  }

  // candidate chunks for this lane's d-columns
  const float* candB = candG + (size_t)b * 64;
  const f32x4 c0a = *(const f32x4*)(candB + kb);
  const f32x4 c0b = *(const f32x4*)(candB + kb + 4);
  const f32x4 c1a = *(const f32x4*)(candB + kb + 32);
  const f32x4 c1b = *(const f32x4*)(candB + kb + 36);

  // loop-invariant layer-1 A-fragments: W1eff^T = (W1a+W1c) + cand_d * W1d
  bf16x8 A1[4][2];
#pragma unroll
  for (int f = 0; f < 8; ++f) {
    const int jt = f >> 1, kc = f & 1;
    bf16x8 ac = *(const bf16x8*)(w1acP + lane * 64 + f * 8);
    bf16x8 dd = *(const bf16x8*)(w1dP  + lane * 64 + f * 8);
    f32x4 cA = kc ? c1a : c0a;
    f32x4 cB = kc ? c1b : c0b;
    bf16x8 o;
#pragma unroll
    for (int e = 0; e < 4; ++e) {
      o[e]     = (__bf16)((float)ac[e]     + cA[e] * (float)dd[e]);
      o[4 + e] = (__bf16)((float)ac[4 + e] + cB[e] * (float)dd[4 + e]);
    }
    A1[jt][kc] = o;
  }

  // layer-2 weight fragments (MFMA A-operand), pre-packed
  bf16x4 W2f[8];
#pragma unroll
  for (int f = 0; f < 8; ++f)
    W2f[f] = *(const bf16x4*)(w2P + lane * 32 + f * 4);

  // exact f32 bias: b1 + cand @ (W1b - W1c)
  float biasv = b1g[lane];
  {
    const float* wdrow = wdifT + lane * 64;
#pragma unroll
    for (int d4 = 0; d4 < 16; ++d4) {
      f32x4 wd = *(const f32x4*)(wdrow + d4 * 4);
      f32x4 cd = *(const f32x4*)(candB + d4 * 4);
      biasv += wd[0] * cd[0] + wd[1] * cd[1] + wd[2] * cd[2] + wd[3] * cd[3];
    }
  }
  // per-lane bias rows for layer-1 C-init: bias[j = jt*16 + g*4 + i]
  f32x4 bj4[4];
#pragma unroll
  for (int jt = 0; jt < 4; ++jt)
#pragma unroll
    for (int i = 0; i < 4; ++i)
      bj4[jt][i] = __shfl(biasv, jt * 16 + g * 4 + i);

  const float al1 = a1g[0];
  const float al2 = a2g[0];
  const f32x4 cinit0 = *(const f32x4*)(b2g + g * 4);
  const f32x4 cinit1 = *(const f32x4*)(b2g + 16 + g * 4);
  const f32x4 w3f0   = *(const f32x4*)(W3g + g * 4);
  const f32x4 w3f1   = *(const f32x4*)(W3g + 16 + g * 4);

  const unsigned char* behB = (const unsigned char*)(behG + (size_t)b * T_LEN * 64);

  // ---- staging geometry ----
  // LINEAR global read: instr k, lane l covers tile bytes [k*1024 + l*16).
  // That chunk is logical (row = 4k + (l>>4), byte off = (l&15)*16).
  // LDS write lands it at swizzled addr row*256 + (off ^ ((row&7)<<4)).
  int srow[4], wrad[4];
#pragma unroll
  for (int k = 0; k < 4; ++k) {
    srow[k] = 4 * k + g;                       // tile-local row this lane stages
    int soff = r * 16;                         // logical byte offset within row
    wrad[k] = srow[k] * 256 + (soff ^ ((srow[k] & 7) << 4));
  }
  // fragment read addresses (lane g,r): logical offs {g*32, g*32+16, 128+g*32, 128+g*32+16}
  int rdad[4];
#pragma unroll
  for (int q = 0; q < 4; ++q) {
    int off = (q >> 1) * 128 + g * 32 + (q & 1) * 16;
    rdad[q] = r * 256 + (off ^ ((r & 7) << 4));
  }

  unsigned char* myb0 = (unsigned char*)&tb[wv][0][0];
  unsigned char* myb1 = (unsigned char*)&tb[wv][1][0];

  // per-lane online-softmax state (lane owns t = mt*16 + r)
  float mrun = -__builtin_inff();
  float srun = 0.f;
  f32x4 o0 = {0,0,0,0}, o1 = {0,0,0,0}, o2 = {0,0,0,0}, o3 = {0,0,0,0};

  f32x4 y[4];
  // prologue: stage tile 0 (linear load -> swizzled LDS write)
#pragma unroll
  for (int k = 0; k < 4; ++k) {
    int gt = srow[k];                           // tile 0: rows 0..15, all valid
    y[k] = *(const f32x4*)(behB + (size_t)gt * 256 + r * 16);
  }
#pragma unroll
  for (int k = 0; k < 4; ++k)
    *(f32x4*)(myb0 + wrad[k]) = y[k];

#pragma unroll 1
  for (int mt = 0; mt < NTILES; ++mt) {
    unsigned char* bufc = (mt & 1) ? myb1 : myb0;
    unsigned char* bufn = (mt & 1) ? myb0 : myb1;

    // issue next tile's LINEAR global loads early (full body of latency slack)
    if (mt + 1 < NTILES) {
#pragma unroll
      for (int k = 0; k < 4; ++k) {
        int gt = (mt + 1) * 16 + srow[k];
        gt = (gt < T_LEN) ? gt : (T_LEN - 1);   // clamp; garbage rows masked later
        y[k] = *(const f32x4*)(behB + (size_t)gt * 256 + r * 16);
      }
    }

    // read this tile's MFMA fragments from LDS (swizzled, bank-balanced)
    f32x4 xc0 = *(const f32x4*)(bufc + rdad[0]);
    f32x4 xc1 = *(const f32x4*)(bufc + rdad[1]);
    f32x4 xc2 = *(const f32x4*)(bufc + rdad[2]);
    f32x4 xc3 = *(const f32x4*)(bufc + rdad[3]);

    bf16x8 ab0, ab1;
#pragma unroll
    for (int i = 0; i < 4; ++i) {
      ab0[i]     = (__bf16)xc0[i];
      ab0[4 + i] = (__bf16)xc1[i];
      ab1[i]     = (__bf16)xc2[i];
      ab1[4 + i] = (__bf16)xc3[i];
    }

    // ---- layer 1 (swapped: D1[j][t]), bias via MFMA C-in ----
    bf16x4 a2f[4];
#pragma unroll
    for (int jt = 0; jt < 4; ++jt) {
      f32x4 acc = MFMA32(A1[jt][0], ab0, bj4[jt]);
      acc = MFMA32(A1[jt][1], ab1, acc);
#pragma unroll
      for (int i = 0; i < 4; ++i) {
        float h = acc[i];
        h = (h >= 0.f) ? h : al1 * h;
        a2f[jt][i] = (__bf16)h;
      }
    }

    // ---- layer 2 SWAPPED: D2[j2][t] = W2^T · h1^T ----
    f32x4 acc20 = cinit0, acc21 = cinit1;
#pragma unroll
    for (int c = 0; c < 4; ++c) acc20 = MFMA16(W2f[c],     a2f[c], acc20);
#pragma unroll
    for (int c = 0; c < 4; ++c) acc21 = MFMA16(W2f[4 + c], a2f[c], acc21);

    // ---- layer 3: in-lane dot + 2-step g-reduce ----
    float partial = 0.f;
#pragma unroll
    for (int i = 0; i < 4; ++i) {
      float h0 = acc20[i]; h0 = (h0 >= 0.f) ? h0 : al2 * h0;
      float h1 = acc21[i]; h1 = (h1 >= 0.f) ? h1 : al2 * h1;
      partial += h0 * w3f0[i] + h1 * w3f1[i];
    }
    partial += __shfl_xor(partial, 16);
    partial += __shfl_xor(partial, 32);
    // partial = logit[t = mt*16 + r], replicated across g

    // ---- per-lane online softmax (defer-max, threshold 8) ----
    const bool valid = ((mbits >> mt) & 1u) != 0u;
    float lvt = valid ? partial : -__builtin_inff();
    if (lvt > mrun + 8.f) {
      float fs = __expf(mrun - lvt); // mrun=-inf -> 0 (zeroes empty state)
      srun *= fs;
#pragma unroll
      for (int i = 0; i < 4; ++i) { o0[i] *= fs; o1[i] *= fs; o2[i] *= fs; o3[i] *= fs; }
      mrun = lvt;
    }
    float et = valid ? __expf(lvt - mrun) : 0.f;
    srun += et;
#pragma unroll
    for (int i = 0; i < 4; ++i) {
      o0[i] += et * (float)ab0[i];
      o1[i] += et * (float)ab0[4 + i];
      o2[i] += et * (float)ab1[i];
      o3[i] += et * (float)ab1[4 + i];
    }

    // stage next tile into the other buffer (vmcnt wait lands here, after compute)
    if (mt + 1 < NTILES) {
#pragma unroll
      for (int k = 0; k < 4; ++k)
        *(f32x4*)(bufn + wrad[k]) = y[k];
    }
  }

  // ---- epilogue: merge the 16 per-lane states across r ----
  float M = mrun;
#pragma unroll
  for (int off = 1; off < 16; off <<= 1) M = fmaxf(M, __shfl_xor(M, off));
  {
    float fac = __expf(mrun - M);   // never-valid lane: exp(-inf)=0
    srun *= fac;
#pragma unroll
    for (int i = 0; i < 4; ++i) { o0[i] *= fac; o1[i] *= fac; o2[i] *= fac; o3[i] *= fac; }
  }
#pragma unroll
  for (int off = 1; off < 16; off <<= 1) {
#pragma unroll
    for (int i = 0; i < 4; ++i) {
      o0[i] += __shfl_xor(o0[i], off);
      o1[i] += __shfl_xor(o1[i], off);
      o2[i] += __shfl_xor(o2[i], off);
      o3[i] += __shfl_xor(o3[i], off);
    }
    srun += __shfl_xor(srun, off);
  }
  if (r == 0) {
    float inv = 1.f / srun;
    float* po = outG + (size_t)b * 64 + kb;
#pragma unroll
    for (int i = 0; i < 4; ++i) {
      o0[i] *= inv; o1[i] *= inv; o2[i] *= inv; o3[i] *= inv;
    }
    *(f32x4*)(po)      = o0;
    *(f32x4*)(po + 4)  = o1;
    *(f32x4*)(po + 32) = o2;
    *(f32x4*)(po + 36) = o3;
  }
}

extern "C" void kernel_launch(void* const* d_in, const int* in_sizes, int n_in,
                              void* d_out, int out_size, void* d_ws, size_t ws_size,
                              hipStream_t stream) {
  (void)n_in; (void)ws_size; (void)out_size;
  const float* beh  = (const float*)d_in[0];
  const float* cand = (const float*)d_in[1];
  const int*   mask = (const int*)d_in[2];
  const float* W1   = (const float*)d_in[3];
  const float* b1   = (const float*)d_in[4];
  const float* a1   = (const float*)d_in[5];
  const float* W2   = (const float*)d_in[6];
  const float* b2   = (const float*)d_in[7];
  const float* a2   = (const float*)d_in[8];
  const float* W3   = (const float*)d_in[9];
  // d_in[10] (b3): uniform additive bias cancels in softmax

  unsigned char* ws = (unsigned char*)d_ws;
  prep_kernel<<<16, 256, 0, stream>>>(W1, W2, ws);

  int B = in_sizes[1] / 64;   // 4096
  int grid = B / 4;           // one wave per batch row, 4 waves per block
  lau_kernel<<<grid, 256, 0, stream>>>(beh, cand, mask, b1, a1, b2, a2, W3,
                                       ws, (float*)d_out);
}